// Round 1
// baseline (1100.383 us; speedup 1.0000x reference)
//
#include <hip/hip_runtime.h>
#include <math.h>

#define H 512
#define W 512
#define NPIX (H * W)          // 262144
#define NB 2
#define NF 180
#define KS 17
#define KR 8
#define TIN 24                // 8 + 2*KR

// ---------------- taps (match numpy float64 _gauss1d) ----------------
__global__ void k_taps(float* __restrict__ taps) {
  if (threadIdx.x == 0 && blockIdx.x == 0) {
    {
      double k[5], s = 0.0;
      for (int i = 0; i < 5; i++) { double xv = (double)(i - 2) / 0.4; k[i] = exp(-0.5 * xv * xv); s += k[i]; }
      for (int i = 0; i < 5; i++) taps[i] = (float)(k[i] / s);
    }
    {
      double k[81], s = 0.0;
      for (int i = 0; i < 81; i++) { double xv = (double)(i - 40) / 10.0; k[i] = exp(-0.5 * xv * xv); s += k[i]; }
      for (int i = 0; i < 81; i++) taps[8 + i] = (float)(k[i] / s);
    }
  }
}

// ---------------- gray ----------------
__global__ void k_gray(const float* __restrict__ x, float* __restrict__ gray) {
  int i = blockIdx.x * blockDim.x + threadIdx.x;
  if (i >= NB * NPIX) return;
  int b = i / NPIX, r = i % NPIX;
  const float* xb = x + (size_t)b * 3 * NPIX;
  gray[i] = 0.2989f * xb[r] + 0.587f * xb[NPIX + r] + 0.114f * xb[2 * NPIX + r];
}

// ---------------- vertical blur, both sigmas fused ----------------
__global__ void k_vblur2(const float* __restrict__ in, float* __restrict__ outA,
                         float* __restrict__ outB, const float* __restrict__ taps) {
  int i = blockIdx.x * blockDim.x + threadIdx.x;
  if (i >= NB * NPIX) return;
  int b = i / NPIX, r = i % NPIX;
  int y = r / W, xx = r % W;
  const float* img = in + (size_t)b * NPIX;
  float a = 0.f;
#pragma unroll
  for (int j = -2; j <= 2; j++) {
    int yy = y + j; yy = yy < 0 ? 0 : (yy > H - 1 ? H - 1 : yy);
    a = fmaf(taps[j + 2], img[yy * W + xx], a);
  }
  float c = 0.f;
  for (int j = -40; j <= 40; j++) {
    int yy = y + j; yy = yy < 0 ? 0 : (yy > H - 1 ? H - 1 : yy);
    c = fmaf(taps[8 + j + 40], img[yy * W + xx], c);
  }
  outA[i] = a;
  outB[i] = c;
}

// ---------------- horizontal blur + DoG ----------------
__global__ void k_hblur_dog(const float* __restrict__ inA, const float* __restrict__ inB,
                            float* __restrict__ dog, const float* __restrict__ taps) {
  int i = blockIdx.x * blockDim.x + threadIdx.x;
  if (i >= NB * NPIX) return;
  int b = i / NPIX, r = i % NPIX;
  int y = r / W, xx = r % W;
  const float* ra = inA + (size_t)b * NPIX + (size_t)y * W;
  const float* rb = inB + (size_t)b * NPIX + (size_t)y * W;
  float a = 0.f;
#pragma unroll
  for (int j = -2; j <= 2; j++) {
    int xc = xx + j; xc = xc < 0 ? 0 : (xc > W - 1 ? W - 1 : xc);
    a = fmaf(taps[j + 2], ra[xc], a);
  }
  float c = 0.f;
  for (int j = -40; j <= 40; j++) {
    int xc = xx + j; xc = xc < 0 ? 0 : (xc > W - 1 ? W - 1 : xc);
    c = fmaf(taps[8 + j + 40], rb[xc], c);
  }
  dog[i] = a - c;
}

// ---------------- main: 180x 17x17 conv + argmax/sum/dist fused ----------------
__launch_bounds__(256)
__global__ void k_gabor(const float* __restrict__ filtered, const float* __restrict__ w,
                        const float* __restrict__ bins, float* __restrict__ out) {
  __shared__ float stile[TIN * TIN];
  __shared__ float resp[NF][64];

  const int b = blockIdx.z;
  const int ty0 = blockIdx.y * 8, tx0 = blockIdx.x * 8;
  const float* img = filtered + (size_t)b * NPIX;

  // cooperative tile load, zero-padded outside the image (conv pad is zeros)
  for (int i = threadIdx.x; i < TIN * TIN; i += 256) {
    int iy = i / TIN, ix = i % TIN;
    int gy = ty0 + iy - KR, gx = tx0 + ix - KR;
    float v = 0.f;
    if (gy >= 0 && gy < H && gx >= 0 && gx < W) v = img[gy * W + gx];
    stile[i] = v;
  }
  __syncthreads();

  const int lane = threadIdx.x & 63;
  const int wv = threadIdx.x >> 6;
  const int f0 = __builtin_amdgcn_readfirstlane(wv * 45);  // wave-uniform filter base
  const int py = lane >> 3, px = lane & 7;

  float acc[45];
#pragma unroll
  for (int f = 0; f < 45; f++) acc[f] = 0.f;

  for (int ky = 0; ky < KS; ky++) {
    float t[KS];
#pragma unroll
    for (int kx = 0; kx < KS; kx++) t[kx] = stile[(py + ky) * TIN + px + kx];
    const float* wr = w + (size_t)f0 * (KS * KS) + ky * KS;
#pragma unroll
    for (int f = 0; f < 45; f++) {
#pragma unroll
      for (int kx = 0; kx < KS; kx++) {
        acc[f] = fmaf(t[kx], wr[f * (KS * KS) + kx], acc[f]);
      }
    }
  }

#pragma unroll
  for (int f = 0; f < 45; f++) resp[f0 + f][lane] = fabsf(acc[f]);
  __syncthreads();

  if (threadIdx.x < 64) {
    const int p = threadIdx.x;
    float m = -1.f, S = 0.f;
    int idx = 0;
    for (int f = 0; f < NF; f++) {
      float r = resp[f][p];
      S += r;
      if (r > m) { m = r; idx = f; }   // first-max-wins, matches jnp.argmax
    }
    const float PI_F = 3.14159265358979323846f;  // rounds to 0x40490FDB
    float om = (float)idx / 180.0f * 255.0f;
    float rad = om / 180.0f * PI_F;
    float C = 0.f;
    for (int f = 0; f < NF; f++) {
      float bn = bins[f];
      float d0 = fabsf(rad - bn);
      float d1 = fabsf(rad - bn - PI_F);
      float d2 = fabsf(rad - bn + PI_F);
      float d = fminf(d0, fminf(d1, d2));
      C = fmaf(d * d, resp[f][p], C);
    }
    int y = ty0 + (p >> 3), x = tx0 + (p & 7);
    out[(size_t)b * NPIX + y * W + x] = om;                      // orientation_map
    out[(size_t)NB * NPIX + (size_t)b * NPIX + y * W + x] = C / S;  // confidence_map
  }
}

extern "C" void kernel_launch(void* const* d_in, const int* in_sizes, int n_in,
                              void* d_out, int out_size, void* d_ws, size_t ws_size,
                              hipStream_t stream) {
  const float* x = (const float*)d_in[0];      // [2,3,512,512]
  const float* wts = (const float*)d_in[1];    // [180,1,17,17]
  const float* bins = (const float*)d_in[2];   // [180]
  float* out = (float*)d_out;                  // 524288 orientation + 524288 confidence

  float* ws = (float*)d_ws;
  float* gray = ws;                       // 524288
  float* tmpA = ws + (size_t)NB * NPIX;   // 524288
  float* tmpB = tmpA + (size_t)NB * NPIX; // 524288
  float* dog  = tmpB + (size_t)NB * NPIX; // 524288
  float* taps = dog + (size_t)NB * NPIX;  // 128

  k_taps<<<1, 64, 0, stream>>>(taps);

  int n = NB * NPIX;
  int blk = 256, grd = (n + blk - 1) / blk;
  k_gray<<<grd, blk, 0, stream>>>(x, gray);
  k_vblur2<<<grd, blk, 0, stream>>>(gray, tmpA, tmpB, taps);
  k_hblur_dog<<<grd, blk, 0, stream>>>(tmpA, tmpB, dog, taps);

  dim3 g(W / 8, H / 8, NB);
  k_gabor<<<g, 256, 0, stream>>>(dog, wts, bins, out);
}